// Round 22
// baseline (219.158 us; speedup 1.0000x reference)
//
#include <hip/hip_runtime.h>
#include <hip/hip_bf16.h>
#include <math.h>

#define B_DIM   4
#define N_DIM   4096
#define D_MODEL 1024
#define D_LOW   32
#define NPAIR   496          // 32*31/2
#define NROWS   (B_DIM * N_DIM)
#define KPAD3   512          // plucker K padded
#define LDA2    1536         // A2 = [x_bf16 | plucker] row stride

typedef __bf16 bf16;
typedef __bf16 bf16x8 __attribute__((ext_vector_type(8)));
typedef __bf16 bf16x4 __attribute__((ext_vector_type(4)));
typedef float  f32x4  __attribute__((ext_vector_type(4)));

#define GLOAD_LDS16(g, l) __builtin_amdgcn_global_load_lds( \
    (__attribute__((address_space(1))) void*)(g),           \
    (__attribute__((address_space(3))) void*)(l), 16, 0, 0)

// ---------------------------------------------------------------------------
// transpose3: one launch.
//  z=0: Wg[0:1024]   -> BcT (Kpad 1536)    z=1: Wg[1024:2048] -> WgbT (1024)
//  z=2: We (496 rows)-> WeT (Kpad 512)     z=3: prep (WrT transpose + WeB)
// ---------------------------------------------------------------------------
__global__ __launch_bounds__(256) void transpose3(const float* __restrict__ Wg,
                                                  const float* __restrict__ We,
                                                  const float* __restrict__ Wr,
                                                  const float* __restrict__ be,
                                                  bf16* __restrict__ BcT,
                                                  bf16* __restrict__ WgbT,
                                                  bf16* __restrict__ WeT,
                                                  bf16* __restrict__ WrT,
                                                  bf16* __restrict__ WeB) {
    __shared__ float tile[32][36];
    const int z = blockIdx.z;
    const int t = threadIdx.x;
    if (z == 3) {
        const int flat = blockIdx.y * 32 + blockIdx.x;
        if (flat >= 544) return;
        if (flat < 32) {
            const int kb = flat * 32;
            {
                int k = t >> 3, c4 = (t & 7) * 4;
                float4 v = *reinterpret_cast<const float4*>(&Wr[(size_t)(kb + k) * 32 + c4]);
                tile[k][c4 + 0] = v.x; tile[k][c4 + 1] = v.y;
                tile[k][c4 + 2] = v.z; tile[k][c4 + 3] = v.w;
            }
            __syncthreads();
            {
                int c = t >> 3, kq = (t & 7) * 4;
                bf16x4 o = { (bf16)tile[kq + 0][c], (bf16)tile[kq + 1][c],
                             (bf16)tile[kq + 2][c], (bf16)tile[kq + 3][c] };
                *reinterpret_cast<bf16x4*>(&WrT[(size_t)c * 1024 + kb + kq]) = o;
            }
        } else {
            size_t o = ((size_t)(flat - 32) * 256 + t) * 4;
            int row = (int)(o >> 10), col = (int)(o & 1023);
            float4 v = {0.f, 0.f, 0.f, 0.f};
            if (row < NPAIR)       v = *reinterpret_cast<const float4*>(&We[(size_t)row * 1024 + col]);
            else if (row == NPAIR) v = *reinterpret_cast<const float4*>(&be[col]);
            bf16x4 b = { (bf16)v.x, (bf16)v.y, (bf16)v.z, (bf16)v.w };
            *reinterpret_cast<bf16x4*>(&WeB[o]) = b;
        }
        return;
    }
    const float* src = (z == 0) ? Wg : (z == 1) ? (Wg + (size_t)1024 * 1024) : We;
    bf16* dst  = (z == 0) ? BcT : (z == 1) ? WgbT : WeT;
    const int Kpad = (z == 0) ? 1536 : (z == 1) ? 1024 : 512;
    const int Ksrc = (z == 2) ? NPAIR : 1024;
    const int kb = blockIdx.x * 32;
    if (kb >= Kpad) return;                  // block-uniform
    const int nb = blockIdx.y * 32;
    int li = t * 4;
    int kl = li >> 5, nl = li & 31;
    float4 v = {0.f, 0.f, 0.f, 0.f};
    if (kb + kl < Ksrc)
        v = *reinterpret_cast<const float4*>(&src[(size_t)(kb + kl) * 1024 + nb + nl]);
    tile[kl][nl + 0] = v.x; tile[kl][nl + 1] = v.y;
    tile[kl][nl + 2] = v.z; tile[kl][nl + 3] = v.w;
    __syncthreads();
    int nl2 = li >> 5, kl2 = li & 31;
    bf16x4 o = { (bf16)tile[kl2 + 0][nl2], (bf16)tile[kl2 + 1][nl2],
                 (bf16)tile[kl2 + 2][nl2], (bf16)tile[kl2 + 3][nl2] };
    *reinterpret_cast<bf16x4*>(&dst[(size_t)(nb + nl2) * Kpad + kb + kl2]) = o;
}

// ---------------------------------------------------------------------------
// wcomb_wave: LDS-free wave-tile GEMM.  C[n][kk] = sum_j WgbT[n][j]*WeB[kk][j]
// -> BcT[n*1536 + 1024 + kk].
// ---------------------------------------------------------------------------
__global__ __launch_bounds__(256) void wcomb_wave(const bf16* __restrict__ WgbT,
                                                  const bf16* __restrict__ WeB,
                                                  bf16* __restrict__ BcT) {
    const int t    = threadIdx.x;
    const int wv   = t >> 6, lane = t & 63;
    const int l15  = lane & 15, lhi = lane >> 4;
    const int kk0  = blockIdx.x * 16;
    const int n0   = blockIdx.y * 64 + wv * 16;
    f32x4 acc = (f32x4){0.f, 0.f, 0.f, 0.f};
#pragma unroll 8
    for (int kb = 0; kb < 1024; kb += 32) {
        const bf16x8 af = *reinterpret_cast<const bf16x8*>(
            &WgbT[(size_t)(n0 + l15) * 1024 + kb + lhi * 8]);
        const bf16x8 bf = *reinterpret_cast<const bf16x8*>(
            &WeB[(size_t)(kk0 + l15) * 1024 + kb + lhi * 8]);
        acc = __builtin_amdgcn_mfma_f32_16x16x32_bf16(af, bf, acc, 0, 0, 0);
    }
#pragma unroll
    for (int r = 0; r < 4; ++r) {
        const int n = n0 + lhi * 4 + r;
        BcT[(size_t)n * 1536 + 1024 + kk0 + l15] = (bf16)acc[r];
    }
}

// ---------------------------------------------------------------------------
// k12: FUSED z-projection + plucker.  256 blocks x 64 own rows.
// Phase 1: z for rows [base-16, base+64) via MFMA (5 row-tiles over 4 waves;
//   wave 0 also does the ghost tile) -> z_lds [80][32]; fused x->bf16 write
//   into A2 cols 0:1024 for OWN rows only.
// Phase 2: k2's plucker per-row (16 rows/wave) from z_lds -> A2 cols 1024+.
// Boundary: ghost z only consumed when tpos>=lag; rows with base%4096==0
// never consume ghost (tpos=row local) -> skip ghost compute there (no OOB).
// ---------------------------------------------------------------------------
__global__ __launch_bounds__(256) void k12(const float* __restrict__ x,
                                           const bf16* __restrict__ WrT,
                                           const float* __restrict__ br,
                                           bf16* __restrict__ a2) {
    __shared__ float z_lds[80][32];
    const int t    = threadIdx.x;
    const int wv   = t >> 6, lane = t & 63;
    const int l15  = lane & 15, lhi = lane >> 4;
    const int mt   = blockIdx.x;
    const int base = mt * 64;

    // ---- phase 1: z tiles ----
    for (int tile = wv; tile < 5; tile += 4) {
        if (tile == 0 && (mt & 63) == 0) continue;   // ghost unused at batch start
        const bool ghost = (tile == 0);
        const int row = base - 16 + tile * 16 + l15;
        f32x4 accz[2] = { (f32x4){0.f,0.f,0.f,0.f}, (f32x4){0.f,0.f,0.f,0.f} };
#pragma unroll 4
        for (int ks = 0; ks < 32; ++ks) {
            const int k0 = ks * 32 + lhi * 8;
            const float4 u0 = *reinterpret_cast<const float4*>(&x[(size_t)row * 1024 + k0]);
            const float4 u1 = *reinterpret_cast<const float4*>(&x[(size_t)row * 1024 + k0 + 4]);
            bf16x8 af = { (bf16)u0.x, (bf16)u0.y, (bf16)u0.z, (bf16)u0.w,
                          (bf16)u1.x, (bf16)u1.y, (bf16)u1.z, (bf16)u1.w };
            if (!ghost)
                *reinterpret_cast<bf16x8*>(&a2[(size_t)row * LDA2 + k0]) = af;
            const bf16x8 b0 = *reinterpret_cast<const bf16x8*>(
                &WrT[(size_t)l15 * 1024 + k0]);
            const bf16x8 b1 = *reinterpret_cast<const bf16x8*>(
                &WrT[(size_t)(16 + l15) * 1024 + k0]);
            accz[0] = __builtin_amdgcn_mfma_f32_16x16x32_bf16(af, b0, accz[0], 0, 0, 0);
            accz[1] = __builtin_amdgcn_mfma_f32_16x16x32_bf16(af, b1, accz[1], 0, 0, 0);
        }
#pragma unroll
        for (int cg = 0; cg < 2; ++cg)
#pragma unroll
            for (int r = 0; r < 4; ++r)
                z_lds[tile * 16 + lhi * 4 + r][cg * 16 + l15] = accz[cg][r];
    }
    __syncthreads();

    // ---- phase 2: plucker, 16 rows per wave ----
    const int c = lane & 31;
    const float bias = br[c];
    for (int i = 0; i < 16; ++i) {
        const int r_loc = wv * 16 + i;
        const int row   = base + r_loc;
        const int tpos  = row & (N_DIM - 1);

        float zc = z_lds[16 + r_loc][c] + bias;
        float zp[4];
        float red[9];
        red[0] = zc * zc;
#pragma unroll
        for (int li = 0; li < 4; ++li) {
            const int lag = 1 << li;
            float v = 0.f;
            if (tpos >= lag) v = z_lds[16 + r_loc - lag][c] + bias;
            zp[li] = v;
            red[1 + li] = zc * zp[li];
            red[5 + li] = zp[li] * zp[li];
        }
#pragma unroll
        for (int m = 1; m < 32; m <<= 1) {
#pragma unroll
            for (int q = 0; q < 9; ++q) red[q] += __shfl_xor(red[q], m);
        }
        float cnt = 0.f;
#pragma unroll
        for (int li = 0; li < 4; ++li) cnt += (tpos >= (1 << li)) ? 1.f : 0.f;
        const float inv = 1.f / fmaxf(cnt, 1.f);

        float w = 0.f;
#pragma unroll
        for (int li = 0; li < 4; ++li) {
            float n2 = fmaxf(red[0] * red[5 + li] - red[1 + li] * red[1 + li], 0.f);
            float nr = sqrtf(n2);
            float s  = (tpos >= (1 << li)) ? inv / fmaxf(nr, 1e-6f) : 0.f;
            w += s * zp[li];
        }

#pragma unroll
        for (int u = 0; u < 8; ++u) {
            const int k = u * 64 + lane;
            float v = 0.f;
            if (k < NPAIR) {
                int kk = k, ii = 0;
                while (kk >= 31 - ii) { kk -= 31 - ii; ++ii; }
                const int j = ii + 1 + kk;
                float zci = __shfl(zc, ii), zcj = __shfl(zc, j);
                float wi  = __shfl(w, ii),  wj  = __shfl(w, j);
                v = zci * wj - zcj * wi;
            }
            a2[(size_t)row * LDA2 + 1024 + k] = (bf16)v;
        }
    }
}

// ---------------------------------------------------------------------------
// FUSED gate GEMM: 128x128 tile, 4 waves (2x2), dbuf 64KB LDS, grid 1024
// -> 2 blocks/CU (R19 optimum).  FROZEN from R21 (passed, 87us, 0 conflicts).
// ---------------------------------------------------------------------------
__global__ __launch_bounds__(256, 2) void gemmfu(const bf16* __restrict__ A,
                                                 const bf16* __restrict__ Bt,
                                                 const bf16* __restrict__ WeT,
                                                 const float* __restrict__ bg,
                                                 const float* __restrict__ be,
                                                 float* __restrict__ out) {
    extern __shared__ char lds[];            // 65536: A 2x16KB | B 2x16KB
    const int t    = threadIdx.x;
    const int w    = t >> 6, lane = t & 63;
    const int wr   = w >> 1, wc = w & 1;     // 2 x 2 wave grid
    const int l15  = lane & 15, lhi = lane >> 4;

    const int fid = blockIdx.x;
    const int xcd = fid & 7, loc = fid >> 3;          // loc 0..127
    const int mb  = (xcd * 16 + (loc >> 3)) * 128;
    const int nb  = (loc & 7) * 128;

    char* const ldsA = lds;                  // + d*16384
    char* const ldsB = lds + 32768;

    const int srow1 = t >> 3;                // 0..31
    const int scol1 = ((t & 7) ^ (srow1 & 7)) * 8;
    const size_t aOff1 = (size_t)(mb + srow1) * LDA2 + scol1;
    const size_t bOff1 = (size_t)(nb + srow1) * 1536 + scol1;
#define STAGE1(d, kb) do { \
    _Pragma("unroll") for (int q = 0; q < 4; ++q) \
        GLOAD_LDS16(A + aOff1 + (size_t)(q * 32) * LDA2 + (kb), \
                    ldsA + (d) * 16384 + q * 4096 + t * 16); \
    _Pragma("unroll") for (int q = 0; q < 4; ++q) \
        GLOAD_LDS16(Bt + bOff1 + (size_t)(q * 32) * 1536 + (kb), \
                    ldsB + (d) * 16384 + q * 4096 + t * 16); } while (0)

    const int srow2 = t >> 2;                // 0..63
    const int scol2 = ((t & 3) ^ ((srow2 >> 1) & 3)) * 8;
    const size_t aOff2 = (size_t)(mb + srow2) * LDA2 + 1024 + scol2;
    const size_t bOff2 = (size_t)(nb + srow2) * 1536 + 1024 + scol2;
    const size_t wOff2 = (size_t)(nb + srow2) * 512 + scol2;
#define STAGE2(d, kb) do { \
    GLOAD_LDS16(A + aOff2 + (kb),                        ldsA + (d) * 16384 + t * 16); \
    GLOAD_LDS16(A + aOff2 + (size_t)64 * LDA2 + (kb),    ldsA + (d) * 16384 + 4096 + t * 16); \
    GLOAD_LDS16(Bt + bOff2 + (kb),                       ldsB + (d) * 16384 + t * 16); \
    GLOAD_LDS16(Bt + bOff2 + (size_t)64 * 1536 + (kb),   ldsB + (d) * 16384 + 4096 + t * 16); \
    GLOAD_LDS16(WeT + wOff2 + (kb),                      ldsB + (d) * 16384 + 8192 + t * 16); \
    GLOAD_LDS16(WeT + wOff2 + (size_t)64 * 512 + (kb),   ldsB + (d) * 16384 + 8192 + 4096 + t * 16); } while (0)

    const int swx1 = (l15 & 7) << 4;
    const int swr2 = ((l15 >> 1) & 3) << 4;

    f32x4 acc[4][4], acc2[4][4];
#pragma unroll
    for (int i = 0; i < 4; ++i)
#pragma unroll
        for (int j = 0; j < 4; ++j) {
            acc[i][j]  = (f32x4){0.f, 0.f, 0.f, 0.f};
            acc2[i][j] = (f32x4){0.f, 0.f, 0.f, 0.f};
        }
    bf16x8 afr[4][2], bfr[4][2];

    STAGE1(0, 0);

    // ---------------- section 1: 16 tiles, BK=64, K in [0,1024) ----------------
    for (int kt = 0; kt < 16; ++kt) {
        const int d = kt & 1;
        asm volatile("s_barrier" ::: "memory");   // BAR_a
        if (kt < 15) {
            STAGE1(d ^ 1, (kt + 1) * 64);
            asm volatile("s_waitcnt vmcnt(8)" ::: "memory");
        } else {
            STAGE2(d ^ 1, 0);
            asm volatile("s_waitcnt vmcnt(6)" ::: "memory");
        }
        asm volatile("s_barrier" ::: "memory");   // BAR_b

        const char* Ab = ldsA + d * 16384;
        const char* Bb = ldsB + d * 16384;
#pragma unroll
        for (int mf = 0; mf < 4; ++mf)
#pragma unroll
            for (int ks = 0; ks < 2; ++ks) {
                int lin = (wr * 64 + mf * 16 + l15) * 128 + ks * 64 + lhi * 16;
                afr[mf][ks] = *reinterpret_cast<const bf16x8*>(Ab + (lin ^ swx1));
            }
#pragma unroll
        for (int nf = 0; nf < 4; ++nf)
#pragma unroll
            for (int ks = 0; ks < 2; ++ks) {
                int lin = (wc * 64 + nf * 16 + l15) * 128 + ks * 64 + lhi * 16;
                bfr[nf][ks] = *reinterpret_cast<const bf16x8*>(Bb + (lin ^ swx1));
            }
        __builtin_amdgcn_s_setprio(1);
#pragma unroll
        for (int mf = 0; mf < 4; ++mf)
#pragma unroll
            for (int nf = 0; nf < 4; ++nf)
#pragma unroll
                for (int ks = 0; ks < 2; ++ks)
                    acc[mf][nf] = __builtin_amdgcn_mfma_f32_16x16x32_bf16(
                        afr[mf][ks], bfr[nf][ks], acc[mf][nf], 0, 0, 0);
        __builtin_amdgcn_s_setprio(0);
    }

    // ---------------- section 2: 16 tiles, BK=32, dual GEMM ----------------
    for (int ft = 0; ft < 16; ++ft) {
        const int d = ft & 1;
        asm volatile("s_barrier" ::: "memory");   // BAR_a
        if (ft < 15) {
            STAGE2(d ^ 1, (ft + 1) * 32);
            asm volatile("s_waitcnt vmcnt(6)" ::: "memory");
        } else {
            asm volatile("s_waitcnt vmcnt(0)" ::: "memory");
        }
        asm volatile("s_barrier" ::: "memory");   // BAR_b

        const char* Ab = ldsA + d * 16384;
        const char* Bb = ldsB + d * 16384;
        bf16x8 a2f[4], bcf[4], wef[4];
#pragma unroll
        for (int mf = 0; mf < 4; ++mf) {
            int lin = (wr * 64 + mf * 16 + l15) * 64 + ((lhi * 16) ^ swr2);
            a2f[mf] = *reinterpret_cast<const bf16x8*>(Ab + lin);
        }
#pragma unroll
        for (int nf = 0; nf < 4; ++nf) {
            int lin = (wc * 64 + nf * 16 + l15) * 64 + ((lhi * 16) ^ swr2);
            bcf[nf] = *reinterpret_cast<const bf16x8*>(Bb + lin);
            wef[nf] = *reinterpret_cast<const bf16x8*>(Bb + 8192 + lin);
        }
        __builtin_amdgcn_s_setprio(1);
#pragma unroll
        for (int mf = 0; mf < 4; ++mf)
#pragma unroll
            for (int nf = 0; nf < 4; ++nf) {
                acc[mf][nf]  = __builtin_amdgcn_mfma_f32_16x16x32_bf16(
                    a2f[mf], bcf[nf], acc[mf][nf], 0, 0, 0);
                acc2[mf][nf] = __builtin_amdgcn_mfma_f32_16x16x32_bf16(
                    a2f[mf], wef[nf], acc2[mf][nf], 0, 0, 0);
            }
        __builtin_amdgcn_s_setprio(0);
    }

    // epilogue: gate + blend
#pragma unroll
    for (int mf = 0; mf < 4; ++mf) {
#pragma unroll
        for (int nf = 0; nf < 4; ++nf) {
            const int col = nb + wc * 64 + nf * 16 + l15;
            const float bgate = bg[col] + (float)Bt[(size_t)col * 1536 + 1024 + NPAIR];
            const float bexp  = be[col];
#pragma unroll
            for (int r = 0; r < 4; ++r) {
                const int row = mb + wr * 64 + mf * 16 + lhi * 4 + r;
                const float s    = acc[mf][nf][r] + bgate;
                const float gate = 1.f / (1.f + expf(-s));
                const float g    = acc2[mf][nf][r] + bexp;
                const float xv   = (float)A[(size_t)row * LDA2 + col];
                out[(size_t)row * D_MODEL + col] = gate * xv + (1.f - gate) * g;
            }
        }
    }
}

// ---------------------------------------------------------------------------
extern "C" void kernel_launch(void* const* d_in, const int* in_sizes, int n_in,
                              void* d_out, int out_size, void* d_ws, size_t ws_size,
                              hipStream_t stream) {
    const float* x  = (const float*)d_in[0];
    const float* Wr = (const float*)d_in[1];
    const float* br = (const float*)d_in[2];
    const float* We = (const float*)d_in[3];
    const float* be = (const float*)d_in[4];
    const float* Wg = (const float*)d_in[5];
    const float* bg = (const float*)d_in[6];
    float* out = (float*)d_out;

    char* ws = (char*)d_ws;
    bf16*  A2    = (bf16*)(ws + (32u << 20));           // 48 MB [16384][1536]
    bf16*  WeT   = (bf16*)(ws + (80u << 20));           //  1 MB [1024][512]
    bf16*  BcT   = (bf16*)(ws + (81u << 20));           //  3 MB [1024][1536]
    bf16*  WgbT  = (bf16*)(ws + (84u << 20));           //  2 MB [1024][1024]
    bf16*  WeB   = (bf16*)(ws + (86u << 20));           //  1 MB [512][1024]
    bf16*  WrT   = (bf16*)(ws + (88u << 20));           // 64 KB [32][1024]

    (void)hipFuncSetAttribute(reinterpret_cast<const void*>(&gemmfu),
                              hipFuncAttributeMaxDynamicSharedMemorySize, 65536);

    // weight prep (1 launch) -> wcomb (1) -> activations (1) -> fused GEMM (1)
    transpose3<<<dim3(32, 32, 4), 256, 0, stream>>>(Wg, We, Wr, be,
                                                    BcT, WgbT, WeT, WrT, WeB);
    wcomb_wave<<<dim3(32, 16), 256, 0, stream>>>(WgbT, WeB, BcT);
    k12<<<256, 256, 0, stream>>>(x, WrT, br, A2);
    gemmfu<<<1024, 256, 65536, stream>>>(A2, BcT, WeT, bg, be, out);
}

// Round 23
// 148.985 us; speedup vs baseline: 1.4710x; 1.4710x over previous
//
#include <hip/hip_runtime.h>
#include <hip/hip_bf16.h>
#include <math.h>

#define B_DIM   4
#define N_DIM   4096
#define D_MODEL 1024
#define D_LOW   32
#define NPAIR   496          // 32*31/2
#define NROWS   (B_DIM * N_DIM)
#define KPAD3   512          // plucker K padded
#define LDA2    1536         // A2 = [x_bf16 | plucker] row stride

typedef __bf16 bf16;
typedef __bf16 bf16x8 __attribute__((ext_vector_type(8)));
typedef __bf16 bf16x4 __attribute__((ext_vector_type(4)));
typedef float  f32x4  __attribute__((ext_vector_type(4)));

#define GLOAD_LDS16(g, l) __builtin_amdgcn_global_load_lds( \
    (__attribute__((address_space(1))) void*)(g),           \
    (__attribute__((address_space(3))) void*)(l), 16, 0, 0)

// ---------------------------------------------------------------------------
// transpose3: one launch.
//  z=0: Wg[0:1024]   -> BcT (Kpad 1536)    z=1: Wg[1024:2048] -> WgbT (1024)
//  z=2: We (496 rows)-> WeT (Kpad 512)     z=3: prep (WrT transpose + WeB)
// ---------------------------------------------------------------------------
__global__ __launch_bounds__(256) void transpose3(const float* __restrict__ Wg,
                                                  const float* __restrict__ We,
                                                  const float* __restrict__ Wr,
                                                  const float* __restrict__ be,
                                                  bf16* __restrict__ BcT,
                                                  bf16* __restrict__ WgbT,
                                                  bf16* __restrict__ WeT,
                                                  bf16* __restrict__ WrT,
                                                  bf16* __restrict__ WeB) {
    __shared__ float tile[32][36];
    const int z = blockIdx.z;
    const int t = threadIdx.x;
    if (z == 3) {
        const int flat = blockIdx.y * 32 + blockIdx.x;
        if (flat >= 544) return;
        if (flat < 32) {
            const int kb = flat * 32;
            {
                int k = t >> 3, c4 = (t & 7) * 4;
                float4 v = *reinterpret_cast<const float4*>(&Wr[(size_t)(kb + k) * 32 + c4]);
                tile[k][c4 + 0] = v.x; tile[k][c4 + 1] = v.y;
                tile[k][c4 + 2] = v.z; tile[k][c4 + 3] = v.w;
            }
            __syncthreads();
            {
                int c = t >> 3, kq = (t & 7) * 4;
                bf16x4 o = { (bf16)tile[kq + 0][c], (bf16)tile[kq + 1][c],
                             (bf16)tile[kq + 2][c], (bf16)tile[kq + 3][c] };
                *reinterpret_cast<bf16x4*>(&WrT[(size_t)c * 1024 + kb + kq]) = o;
            }
        } else {
            size_t o = ((size_t)(flat - 32) * 256 + t) * 4;
            int row = (int)(o >> 10), col = (int)(o & 1023);
            float4 v = {0.f, 0.f, 0.f, 0.f};
            if (row < NPAIR)       v = *reinterpret_cast<const float4*>(&We[(size_t)row * 1024 + col]);
            else if (row == NPAIR) v = *reinterpret_cast<const float4*>(&be[col]);
            bf16x4 b = { (bf16)v.x, (bf16)v.y, (bf16)v.z, (bf16)v.w };
            *reinterpret_cast<bf16x4*>(&WeB[o]) = b;
        }
        return;
    }
    const float* src = (z == 0) ? Wg : (z == 1) ? (Wg + (size_t)1024 * 1024) : We;
    bf16* dst  = (z == 0) ? BcT : (z == 1) ? WgbT : WeT;
    const int Kpad = (z == 0) ? 1536 : (z == 1) ? 1024 : 512;
    const int Ksrc = (z == 2) ? NPAIR : 1024;
    const int kb = blockIdx.x * 32;
    if (kb >= Kpad) return;                  // block-uniform
    const int nb = blockIdx.y * 32;
    int li = t * 4;
    int kl = li >> 5, nl = li & 31;
    float4 v = {0.f, 0.f, 0.f, 0.f};
    if (kb + kl < Ksrc)
        v = *reinterpret_cast<const float4*>(&src[(size_t)(kb + kl) * 1024 + nb + nl]);
    tile[kl][nl + 0] = v.x; tile[kl][nl + 1] = v.y;
    tile[kl][nl + 2] = v.z; tile[kl][nl + 3] = v.w;
    __syncthreads();
    int nl2 = li >> 5, kl2 = li & 31;
    bf16x4 o = { (bf16)tile[kl2 + 0][nl2], (bf16)tile[kl2 + 1][nl2],
                 (bf16)tile[kl2 + 2][nl2], (bf16)tile[kl2 + 3][nl2] };
    *reinterpret_cast<bf16x4*>(&dst[(size_t)(nb + nl2) * Kpad + kb + kl2]) = o;
}

// ---------------------------------------------------------------------------
// wcomb_wave: LDS-free wave-tile GEMM.  C[n][kk] = sum_j WgbT[n][j]*WeB[kk][j]
// -> BcT[n*1536 + 1024 + kk].
// ---------------------------------------------------------------------------
__global__ __launch_bounds__(256) void wcomb_wave(const bf16* __restrict__ WgbT,
                                                  const bf16* __restrict__ WeB,
                                                  bf16* __restrict__ BcT) {
    const int t    = threadIdx.x;
    const int wv   = t >> 6, lane = t & 63;
    const int l15  = lane & 15, lhi = lane >> 4;
    const int kk0  = blockIdx.x * 16;
    const int n0   = blockIdx.y * 64 + wv * 16;
    f32x4 acc = (f32x4){0.f, 0.f, 0.f, 0.f};
#pragma unroll 8
    for (int kb = 0; kb < 1024; kb += 32) {
        const bf16x8 af = *reinterpret_cast<const bf16x8*>(
            &WgbT[(size_t)(n0 + l15) * 1024 + kb + lhi * 8]);
        const bf16x8 bf = *reinterpret_cast<const bf16x8*>(
            &WeB[(size_t)(kk0 + l15) * 1024 + kb + lhi * 8]);
        acc = __builtin_amdgcn_mfma_f32_16x16x32_bf16(af, bf, acc, 0, 0, 0);
    }
#pragma unroll
    for (int r = 0; r < 4; ++r) {
        const int n = n0 + lhi * 4 + r;
        BcT[(size_t)n * 1536 + 1024 + kk0 + l15] = (bf16)acc[r];
    }
}

// ---------------------------------------------------------------------------
// k1_mfma: zpart[kchunk] = x[:, chunk] @ W_red[chunk, :]  (split-K = 4)
// fused: a2[:, chunk] = bf16(x[:, chunk])   (R21 proven, grid (4,256))
// ---------------------------------------------------------------------------
__global__ __launch_bounds__(256) void k1_mfma(const float* __restrict__ x,
                                               const bf16* __restrict__ WrT,
                                               bf16* __restrict__ a2,
                                               float* __restrict__ zpart) {
    const int t    = threadIdx.x;
    const int wv   = t >> 6, lane = t & 63;
    const int l15  = lane & 15, lhi = lane >> 4;
    const int kc   = blockIdx.x;
    const int mt   = blockIdx.y;
    const int row  = mt * 64 + wv * 16 + l15;   // A-fragment row
    const int kb   = kc * 256;

    f32x4 accz[2] = { (f32x4){0.f,0.f,0.f,0.f}, (f32x4){0.f,0.f,0.f,0.f} };

#pragma unroll
    for (int ks = 0; ks < 8; ++ks) {
        const int k0 = kb + ks * 32 + lhi * 8;
        const float4 u0 = *reinterpret_cast<const float4*>(&x[(size_t)row * 1024 + k0]);
        const float4 u1 = *reinterpret_cast<const float4*>(&x[(size_t)row * 1024 + k0 + 4]);
        bf16x8 af = { (bf16)u0.x, (bf16)u0.y, (bf16)u0.z, (bf16)u0.w,
                      (bf16)u1.x, (bf16)u1.y, (bf16)u1.z, (bf16)u1.w };
        *reinterpret_cast<bf16x8*>(&a2[(size_t)row * LDA2 + k0]) = af;
        const bf16x8 b0 = *reinterpret_cast<const bf16x8*>(
            &WrT[(size_t)l15 * 1024 + kb + ks * 32 + lhi * 8]);
        const bf16x8 b1 = *reinterpret_cast<const bf16x8*>(
            &WrT[(size_t)(16 + l15) * 1024 + kb + ks * 32 + lhi * 8]);
        accz[0] = __builtin_amdgcn_mfma_f32_16x16x32_bf16(af, b0, accz[0], 0, 0, 0);
        accz[1] = __builtin_amdgcn_mfma_f32_16x16x32_bf16(af, b1, accz[1], 0, 0, 0);
    }
#pragma unroll
    for (int cg = 0; cg < 2; ++cg)
#pragma unroll
        for (int r = 0; r < 4; ++r) {
            const int rout = mt * 64 + wv * 16 + lhi * 4 + r;
            zpart[((size_t)kc * NROWS + rout) * 32 + cg * 16 + l15] = accz[cg][r];
        }
}

// ---------------------------------------------------------------------------
// K2: plucker_avg -> bf16 into A2[:, 1024:1536].  z = bias + sum_p zpart[p].
// (R21 proven, grid NROWS/4)
// ---------------------------------------------------------------------------
__global__ __launch_bounds__(256) void k2_plucker(const float* __restrict__ zpart,
                                                  const float* __restrict__ br,
                                                  bf16* __restrict__ a2) {
    const int wv   = threadIdx.x >> 6;
    const int lane = threadIdx.x & 63;
    const int row  = blockIdx.x * 4 + wv;
    const int t    = row & (N_DIM - 1);
    const int c    = lane & 31;
    const float bias = br[c];

    float zc = bias;
#pragma unroll
    for (int p = 0; p < 4; ++p)
        zc += zpart[((size_t)p * NROWS + row) * 32 + c];

    float zp[4];
    float red[9];
    red[0] = zc * zc;
#pragma unroll
    for (int li = 0; li < 4; ++li) {
        const int lag = 1 << li;
        float v = 0.f;
        if (t >= lag) {
            v = bias;
#pragma unroll
            for (int p = 0; p < 4; ++p)
                v += zpart[((size_t)p * NROWS + (row - lag)) * 32 + c];
        }
        zp[li] = v;
        red[1 + li] = zc * zp[li];
        red[5 + li] = zp[li] * zp[li];
    }
#pragma unroll
    for (int m = 1; m < 32; m <<= 1) {
#pragma unroll
        for (int i = 0; i < 9; ++i) red[i] += __shfl_xor(red[i], m);
    }
    float cnt = 0.f;
#pragma unroll
    for (int li = 0; li < 4; ++li) cnt += (t >= (1 << li)) ? 1.f : 0.f;
    const float inv = 1.f / fmaxf(cnt, 1.f);

    float w = 0.f;
#pragma unroll
    for (int li = 0; li < 4; ++li) {
        float n2 = fmaxf(red[0] * red[5 + li] - red[1 + li] * red[1 + li], 0.f);
        float nr = sqrtf(n2);
        float s  = (t >= (1 << li)) ? inv / fmaxf(nr, 1e-6f) : 0.f;
        w += s * zp[li];
    }

#pragma unroll
    for (int u = 0; u < 8; ++u) {
        const int k = u * 64 + lane;
        float v = 0.f;
        if (k < NPAIR) {
            int kk = k, i = 0;
            while (kk >= 31 - i) { kk -= 31 - i; ++i; }
            const int j = i + 1 + kk;
            float zci = __shfl(zc, i), zcj = __shfl(zc, j);
            float wi  = __shfl(w, i),  wj  = __shfl(w, j);
            v = zci * wj - zcj * wi;
        }
        a2[(size_t)row * LDA2 + 1024 + k] = (bf16)v;
    }
}

// ---------------------------------------------------------------------------
// FUSED gate GEMM: 128x128 tile, 4 waves (2x2), dbuf 64KB LDS, grid 1024
// -> 2 blocks/CU (R19 optimum).  FROZEN from R21 (passed, 87us, 0 conflicts).
// ---------------------------------------------------------------------------
__global__ __launch_bounds__(256, 2) void gemmfu(const bf16* __restrict__ A,
                                                 const bf16* __restrict__ Bt,
                                                 const bf16* __restrict__ WeT,
                                                 const float* __restrict__ bg,
                                                 const float* __restrict__ be,
                                                 float* __restrict__ out) {
    extern __shared__ char lds[];            // 65536: A 2x16KB | B 2x16KB
    const int t    = threadIdx.x;
    const int w    = t >> 6, lane = t & 63;
    const int wr   = w >> 1, wc = w & 1;     // 2 x 2 wave grid
    const int l15  = lane & 15, lhi = lane >> 4;

    const int fid = blockIdx.x;
    const int xcd = fid & 7, loc = fid >> 3;          // loc 0..127
    const int mb  = (xcd * 16 + (loc >> 3)) * 128;
    const int nb  = (loc & 7) * 128;

    char* const ldsA = lds;                  // + d*16384
    char* const ldsB = lds + 32768;

    const int srow1 = t >> 3;                // 0..31
    const int scol1 = ((t & 7) ^ (srow1 & 7)) * 8;
    const size_t aOff1 = (size_t)(mb + srow1) * LDA2 + scol1;
    const size_t bOff1 = (size_t)(nb + srow1) * 1536 + scol1;
#define STAGE1(d, kb) do { \
    _Pragma("unroll") for (int q = 0; q < 4; ++q) \
        GLOAD_LDS16(A + aOff1 + (size_t)(q * 32) * LDA2 + (kb), \
                    ldsA + (d) * 16384 + q * 4096 + t * 16); \
    _Pragma("unroll") for (int q = 0; q < 4; ++q) \
        GLOAD_LDS16(Bt + bOff1 + (size_t)(q * 32) * 1536 + (kb), \
                    ldsB + (d) * 16384 + q * 4096 + t * 16); } while (0)

    const int srow2 = t >> 2;                // 0..63
    const int scol2 = ((t & 3) ^ ((srow2 >> 1) & 3)) * 8;
    const size_t aOff2 = (size_t)(mb + srow2) * LDA2 + 1024 + scol2;
    const size_t bOff2 = (size_t)(nb + srow2) * 1536 + 1024 + scol2;
    const size_t wOff2 = (size_t)(nb + srow2) * 512 + scol2;
#define STAGE2(d, kb) do { \
    GLOAD_LDS16(A + aOff2 + (kb),                        ldsA + (d) * 16384 + t * 16); \
    GLOAD_LDS16(A + aOff2 + (size_t)64 * LDA2 + (kb),    ldsA + (d) * 16384 + 4096 + t * 16); \
    GLOAD_LDS16(Bt + bOff2 + (kb),                       ldsB + (d) * 16384 + t * 16); \
    GLOAD_LDS16(Bt + bOff2 + (size_t)64 * 1536 + (kb),   ldsB + (d) * 16384 + 4096 + t * 16); \
    GLOAD_LDS16(WeT + wOff2 + (kb),                      ldsB + (d) * 16384 + 8192 + t * 16); \
    GLOAD_LDS16(WeT + wOff2 + (size_t)64 * 512 + (kb),   ldsB + (d) * 16384 + 8192 + 4096 + t * 16); } while (0)

    const int swx1 = (l15 & 7) << 4;
    const int swr2 = ((l15 >> 1) & 3) << 4;

    f32x4 acc[4][4], acc2[4][4];
#pragma unroll
    for (int i = 0; i < 4; ++i)
#pragma unroll
        for (int j = 0; j < 4; ++j) {
            acc[i][j]  = (f32x4){0.f, 0.f, 0.f, 0.f};
            acc2[i][j] = (f32x4){0.f, 0.f, 0.f, 0.f};
        }
    bf16x8 afr[4][2], bfr[4][2];

    STAGE1(0, 0);

    // ---------------- section 1: 16 tiles, BK=64, K in [0,1024) ----------------
    for (int kt = 0; kt < 16; ++kt) {
        const int d = kt & 1;
        asm volatile("s_barrier" ::: "memory");   // BAR_a
        if (kt < 15) {
            STAGE1(d ^ 1, (kt + 1) * 64);
            asm volatile("s_waitcnt vmcnt(8)" ::: "memory");
        } else {
            STAGE2(d ^ 1, 0);
            asm volatile("s_waitcnt vmcnt(6)" ::: "memory");
        }
        asm volatile("s_barrier" ::: "memory");   // BAR_b

        const char* Ab = ldsA + d * 16384;
        const char* Bb = ldsB + d * 16384;
#pragma unroll
        for (int mf = 0; mf < 4; ++mf)
#pragma unroll
            for (int ks = 0; ks < 2; ++ks) {
                int lin = (wr * 64 + mf * 16 + l15) * 128 + ks * 64 + lhi * 16;
                afr[mf][ks] = *reinterpret_cast<const bf16x8*>(Ab + (lin ^ swx1));
            }
#pragma unroll
        for (int nf = 0; nf < 4; ++nf)
#pragma unroll
            for (int ks = 0; ks < 2; ++ks) {
                int lin = (wc * 64 + nf * 16 + l15) * 128 + ks * 64 + lhi * 16;
                bfr[nf][ks] = *reinterpret_cast<const bf16x8*>(Bb + (lin ^ swx1));
            }
        __builtin_amdgcn_s_setprio(1);
#pragma unroll
        for (int mf = 0; mf < 4; ++mf)
#pragma unroll
            for (int nf = 0; nf < 4; ++nf)
#pragma unroll
                for (int ks = 0; ks < 2; ++ks)
                    acc[mf][nf] = __builtin_amdgcn_mfma_f32_16x16x32_bf16(
                        afr[mf][ks], bfr[nf][ks], acc[mf][nf], 0, 0, 0);
        __builtin_amdgcn_s_setprio(0);
    }

    // ---------------- section 2: 16 tiles, BK=32, dual GEMM ----------------
    for (int ft = 0; ft < 16; ++ft) {
        const int d = ft & 1;
        asm volatile("s_barrier" ::: "memory");   // BAR_a
        if (ft < 15) {
            STAGE2(d ^ 1, (ft + 1) * 32);
            asm volatile("s_waitcnt vmcnt(6)" ::: "memory");
        } else {
            asm volatile("s_waitcnt vmcnt(0)" ::: "memory");
        }
        asm volatile("s_barrier" ::: "memory");   // BAR_b

        const char* Ab = ldsA + d * 16384;
        const char* Bb = ldsB + d * 16384;
        bf16x8 a2f[4], bcf[4], wef[4];
#pragma unroll
        for (int mf = 0; mf < 4; ++mf) {
            int lin = (wr * 64 + mf * 16 + l15) * 64 + ((lhi * 16) ^ swr2);
            a2f[mf] = *reinterpret_cast<const bf16x8*>(Ab + lin);
        }
#pragma unroll
        for (int nf = 0; nf < 4; ++nf) {
            int lin = (wc * 64 + nf * 16 + l15) * 64 + ((lhi * 16) ^ swr2);
            bcf[nf] = *reinterpret_cast<const bf16x8*>(Bb + lin);
            wef[nf] = *reinterpret_cast<const bf16x8*>(Bb + 8192 + lin);
        }
        __builtin_amdgcn_s_setprio(1);
#pragma unroll
        for (int mf = 0; mf < 4; ++mf)
#pragma unroll
            for (int nf = 0; nf < 4; ++nf) {
                acc[mf][nf]  = __builtin_amdgcn_mfma_f32_16x16x32_bf16(
                    a2f[mf], bcf[nf], acc[mf][nf], 0, 0, 0);
                acc2[mf][nf] = __builtin_amdgcn_mfma_f32_16x16x32_bf16(
                    a2f[mf], wef[nf], acc2[mf][nf], 0, 0, 0);
            }
        __builtin_amdgcn_s_setprio(0);
    }

    // epilogue: gate + blend
#pragma unroll
    for (int mf = 0; mf < 4; ++mf) {
#pragma unroll
        for (int nf = 0; nf < 4; ++nf) {
            const int col = nb + wc * 64 + nf * 16 + l15;
            const float bgate = bg[col] + (float)Bt[(size_t)col * 1536 + 1024 + NPAIR];
            const float bexp  = be[col];
#pragma unroll
            for (int r = 0; r < 4; ++r) {
                const int row = mb + wr * 64 + mf * 16 + lhi * 4 + r;
                const float s    = acc[mf][nf][r] + bgate;
                const float gate = 1.f / (1.f + expf(-s));
                const float g    = acc2[mf][nf][r] + bexp;
                const float xv   = (float)A[(size_t)row * LDA2 + col];
                out[(size_t)row * D_MODEL + col] = gate * xv + (1.f - gate) * g;
            }
        }
    }
}

// ---------------------------------------------------------------------------
extern "C" void kernel_launch(void* const* d_in, const int* in_sizes, int n_in,
                              void* d_out, int out_size, void* d_ws, size_t ws_size,
                              hipStream_t stream) {
    const float* x  = (const float*)d_in[0];
    const float* Wr = (const float*)d_in[1];
    const float* br = (const float*)d_in[2];
    const float* We = (const float*)d_in[3];
    const float* be = (const float*)d_in[4];
    const float* Wg = (const float*)d_in[5];
    const float* bg = (const float*)d_in[6];
    float* out = (float*)d_out;

    char* ws = (char*)d_ws;
    float* zpart = (float*)(ws);                        //  8 MB [4][16384][32]
    bf16*  A2    = (bf16*)(ws + (32u << 20));           // 48 MB [16384][1536]
    bf16*  WeT   = (bf16*)(ws + (80u << 20));           //  1 MB [1024][512]
    bf16*  BcT   = (bf16*)(ws + (81u << 20));           //  3 MB [1024][1536]
    bf16*  WgbT  = (bf16*)(ws + (84u << 20));           //  2 MB [1024][1024]
    bf16*  WeB   = (bf16*)(ws + (86u << 20));           //  1 MB [512][1024]
    bf16*  WrT   = (bf16*)(ws + (88u << 20));           // 64 KB [32][1024]

    (void)hipFuncSetAttribute(reinterpret_cast<const void*>(&gemmfu),
                              hipFuncAttributeMaxDynamicSharedMemorySize, 65536);

    // weight prep (1) -> wcomb (1) -> activations (2) -> fused GEMM (1)
    transpose3<<<dim3(32, 32, 4), 256, 0, stream>>>(Wg, We, Wr, be,
                                                    BcT, WgbT, WeT, WrT, WeB);
    wcomb_wave<<<dim3(32, 16), 256, 0, stream>>>(WgbT, WeB, BcT);
    k1_mfma<<<dim3(4, 256), 256, 0, stream>>>(x, WrT, A2, zpart);
    k2_plucker<<<NROWS / 4, 256, 0, stream>>>(zpart, br, A2);
    gemmfu<<<1024, 256, 65536, stream>>>(A2, BcT, WeT, bg, be, out);
}